// Round 13
// baseline (3248.520 us; speedup 1.0000x reference)
//
#include <hip/hip_runtime.h>
#include <hip/hip_bf16.h>
#include <stdint.h>

#define B_ 128
#define T_ 512
#define D_ 1024
#define H_ 1024

typedef __attribute__((ext_vector_type(8))) short bf16x8;
typedef __attribute__((ext_vector_type(4))) float f32x4;
typedef unsigned int u32;
typedef __attribute__((ext_vector_type(4))) u32 u32x4;

__device__ __forceinline__ ushort f2bf(float f) {
  union { float f; uint32_t u; } v; v.f = f;
  uint32_t u = v.u + 0x7FFFu + ((v.u >> 16) & 1u);
  return (ushort)(u >> 16);
}
__device__ __forceinline__ float bf2f(ushort s) {
  union { uint32_t u; float f; } v; v.u = ((uint32_t)s) << 16;
  return v.f;
}

// ---------------- W_hh -> (hi, lo) bf16 split ----------------
__global__ void wsplit_kernel(const float* __restrict__ W,
                              ushort* __restrict__ hi, ushort* __restrict__ lo,
                              int n) {
  int i = blockIdx.x * blockDim.x + threadIdx.x;
  if (i < n) {
    float w = W[i];
    ushort h = f2bf(w);
    hi[i] = h;
    lo[i] = f2bf(w - bf2f(h));
  }
}

// ---------------- zero workspace region ----------------
__global__ void hzero_kernel(uint4* __restrict__ p, int n4) {
  int i = blockIdx.x * blockDim.x + threadIdx.x;
  if (i < n4) p[i] = make_uint4(0, 0, 0, 0);
}

// ============ FUSED kernel: xp-GEMM (waves 4-7) + recurrence (waves 0-3) ============
// 256 WGs x 512 threads. rep = bid&7 (16 batches), wgc = bid>>3 (32 cols).
// Persist waves: EXACT round-11 structure (packed-u32 coalesced gather + LDS
// restage + swizzle + perm unpack; plain-store posts; per-wave producer poll;
// one __syncthreads per step = 512 barriers). Additions: xp loads are sc0 sc1
// (produced intra-kernel, possibly cross-XCD), and a per-band xp-flag poll
// every 64 steps.
// Gemm waves: each computes 16 tiles (64Mx64N, K=1024) of xp for THIS replica,
// t-band-major (2 tiles/band), into wave-private padded LDS (no barriers
// inside tiles). Stores xp + bias with sc0 sc1, vmcnt(0), posts per-tile flag.
// One __syncthreads per band (8) + 504 fillers = 512 barriers (matches).
// Deadlock-free: band-0 flags post BEFORE gemm's barrier #1; persist's step-0
// poll therefore completes; every gemm barrier is preceded by compute only.
__global__ __launch_bounds__(512, 2) void rnn_fused(
    const float* __restrict__ x, const float* __restrict__ Wih,
    const float* __restrict__ bih, const float* __restrict__ bhh,
    const ushort* __restrict__ Whi, const ushort* __restrict__ Wlo,
    float* __restrict__ xp,
    u32* __restrict__ hpk,     // [2][B_][H_] packed bf16 hi|lo
    u32* __restrict__ cnt,     // [256][16] per-WG counter lines, slots 0..3
    u32* __restrict__ xpflag,  // [128][8][16] tile flags (b, t6, bn64)
    float* __restrict__ out) {
  __shared__ __align__(16) u32 stage[4 * 16 * 256];      // 64 KB (persist)
  __shared__ __align__(16) ushort gsA[4][64 * 40];       // 20 KB (gemm, pad 40)
  __shared__ __align__(16) ushort gsB[4][64 * 40];       // 20 KB
  __shared__ __align__(16) f32x4 red[2][4][2][64];       // 16 KB

  const int bid = blockIdx.x;
  const int rep = bid & 7;
  const int wgc = bid >> 3;
  const int tid = threadIdx.x;
  const int lane = tid & 63;
  const int wid = tid >> 6;
  const int r16 = lane & 15;
  const int kg = lane >> 4;

  if (wid < 4) {
    // ================= PERSIST ROLE (round-11 verbatim + xp changes) ==========
    const int kq = wid;
    const int nf_e = kq & 1;
    const int rh_e = kq >> 1;
    const int l5 = lane & 31;

    bf16x8 wbh[8][2], wbl[8][2];
#pragma unroll
    for (int ks = 0; ks < 8; ++ks) {
#pragma unroll
      for (int nf = 0; nf < 2; ++nf) {
        int col = wgc * 32 + nf * 16 + r16;
        int k = kq * 256 + ks * 32 + kg * 8;
        wbh[ks][nf] = *(const bf16x8*)(Whi + (size_t)col * H_ + k);
        wbl[ks][nf] = *(const bf16x8*)(Wlo + (size_t)col * H_ + k);
      }
    }

    const int erow0 = rep * 16 + kg * 4 + rh_e * 2;
    const int ecol = wgc * 32 + nf_e * 16 + r16;
    u32* mypost = cnt + (size_t)(rep * 32 + wgc) * 16 + kq;
    const u32* mypoll = cnt + (size_t)(rep * 32 + kq * 8 + (l5 >> 2)) * 16 + (l5 & 3);
    const u32* bandflag = xpflag + ((size_t)(rep * 16 + r16) * 8) * 16 + (wgc >> 1);
    const int sbase = kq * (16 * 256);

    for (int t = 0; t < T_; ++t) {
      const u32* Hq = hpk + (size_t)(t & 1) * (B_ * H_);
      u32* Hn = hpk + (size_t)((t + 1) & 1) * (B_ * H_);

      // xp band readiness (every 64 steps): 16 b-flags for (t>>6, wgc>>1)
      if ((t & 63) == 0) {
        const u32* fp = bandflag + (size_t)(t >> 6) * 16;
        for (;;) {
          u32 v = __hip_atomic_load(fp, __ATOMIC_RELAXED, __HIP_MEMORY_SCOPE_AGENT);
          if (__all((int)(v != 0u))) break;
          __builtin_amdgcn_s_sleep(1);
        }
      }

      // h producer poll
      if (t) {
        const u32 target = (u32)t;
        for (;;) {
          u32 v = __hip_atomic_load(mypoll, __ATOMIC_RELAXED, __HIP_MEMORY_SCOPE_AGENT);
          if (__all((int)(v >= target))) break;
          __builtin_amdgcn_s_sleep(1);
        }
      }

      // xp loads (sc0 sc1: intra-kernel producer, possibly cross-XCD); oldest
      u32 xr0, xr1;
      {
        const float* p0 = xp + (size_t)t * (B_ * H_) + (size_t)erow0 * H_ + ecol;
        const float* p1 = p0 + H_;
        asm volatile("global_load_dword %0, %1, off sc0 sc1" : "=&v"(xr0) : "v"(p0) : "memory");
        asm volatile("global_load_dword %0, %1, off sc0 sc1" : "=&v"(xr1) : "v"(p1) : "memory");
      }

      // coalesced gather of the wave's 16x256 packed quarter
      u32x4 g[16];
      {
        const u32* gb = Hq + (size_t)rep * 16 * H_ + kq * 256 + lane * 4;
#pragma unroll
        for (int i = 0; i < 16; ++i) {
          const u32* a = gb + (size_t)i * H_;
          asm volatile("global_load_dwordx4 %0, %1, off sc0 sc1"
                       : "=&v"(g[i]) : "v"(a) : "memory");
        }
      }
      asm volatile("s_waitcnt vmcnt(8)" ::: "memory");
      __builtin_amdgcn_sched_barrier(0);
#pragma unroll
      for (int i = 0; i < 8; ++i) {
        int idx = sbase + i * 256 + ((lane * 4) ^ ((i & 7) << 2));
        *(u32x4*)&stage[idx] = g[i];
      }
      asm volatile("s_waitcnt vmcnt(0)" ::: "memory");
      __builtin_amdgcn_sched_barrier(0);
#pragma unroll
      for (int i = 8; i < 16; ++i) {
        int idx = sbase + i * 256 + ((lane * 4) ^ ((i & 7) << 2));
        *(u32x4*)&stage[idx] = g[i];
      }

      f32x4 acc[2] = {};
      const int rbase = sbase + r16 * 256;
      const int s = (r16 & 7) << 2;
#pragma unroll
      for (int ks = 0; ks < 8; ++ks) {
        int colq = ks * 32 + kg * 8;
        u32x4 d0 = *(const u32x4*)&stage[rbase + ((colq) ^ s)];
        u32x4 d1 = *(const u32x4*)&stage[rbase + ((colq + 4) ^ s)];
        union { u32 u[4]; bf16x8 v; } ah, al;
        ah.u[0] = __builtin_amdgcn_perm(d0[1], d0[0], 0x05040100u);
        ah.u[1] = __builtin_amdgcn_perm(d0[3], d0[2], 0x05040100u);
        ah.u[2] = __builtin_amdgcn_perm(d1[1], d1[0], 0x05040100u);
        ah.u[3] = __builtin_amdgcn_perm(d1[3], d1[2], 0x05040100u);
        al.u[0] = __builtin_amdgcn_perm(d0[1], d0[0], 0x07060302u);
        al.u[1] = __builtin_amdgcn_perm(d0[3], d0[2], 0x07060302u);
        al.u[2] = __builtin_amdgcn_perm(d1[1], d1[0], 0x07060302u);
        al.u[3] = __builtin_amdgcn_perm(d1[3], d1[2], 0x07060302u);
#pragma unroll
        for (int nf = 0; nf < 2; ++nf) {
          acc[nf] = __builtin_amdgcn_mfma_f32_16x16x32_bf16(ah.v, wbh[ks][nf], acc[nf], 0, 0, 0);
          acc[nf] = __builtin_amdgcn_mfma_f32_16x16x32_bf16(al.v, wbh[ks][nf], acc[nf], 0, 0, 0);
          acc[nf] = __builtin_amdgcn_mfma_f32_16x16x32_bf16(ah.v, wbl[ks][nf], acc[nf], 0, 0, 0);
        }
      }

      const int par = t & 1;
      red[par][kq][0][lane] = acc[0];
      red[par][kq][1][lane] = acc[1];
      __syncthreads();   // barrier 1-of-512 per wave (all 8 waves)

      {
        f32x4 sum = red[par][0][nf_e][lane];
        sum += red[par][1][nf_e][lane];
        sum += red[par][2][nf_e][lane];
        sum += red[par][3][nf_e][lane];
        float s0 = rh_e ? sum[2] : sum[0];
        float s1 = rh_e ? sum[3] : sum[1];
        union { u32 u; float f; } c0, c1; c0.u = xr0; c1.u = xr1;
        float h0 = tanhf(s0 + c0.f);
        float h1 = tanhf(s1 + c1.f);
        ushort hb0 = f2bf(h0), hb1 = f2bf(h1);
        u32 pk0 = (u32)hb0 | ((u32)f2bf(h0 - bf2f(hb0)) << 16);
        u32 pk1 = (u32)hb1 | ((u32)f2bf(h1 - bf2f(hb1)) << 16);
        __hip_atomic_store(Hn + (size_t)erow0 * H_ + ecol, pk0,
                           __ATOMIC_RELAXED, __HIP_MEMORY_SCOPE_AGENT);
        __hip_atomic_store(Hn + (size_t)(erow0 + 1) * H_ + ecol, pk1,
                           __ATOMIC_RELAXED, __HIP_MEMORY_SCOPE_AGENT);
        if (t == T_ - 1) {
          out[(size_t)erow0 * H_ + ecol] = h0;
          out[(size_t)(erow0 + 1) * H_ + ecol] = h1;
        }
      }

      asm volatile("s_waitcnt vmcnt(0)" ::: "memory");
      __builtin_amdgcn_sched_barrier(0);
      if (lane == 0)
        __hip_atomic_store(mypost, (u32)(t + 1),
                           __ATOMIC_RELAXED, __HIP_MEMORY_SCOPE_AGENT);
    }
  } else {
    // ================= GEMM ROLE ==============================================
    const int gw = wid - 4;                 // 0..3
    const int wrep = wgc * 4 + gw;          // 0..127 within replica
    const int r4 = lane >> 2;               // 0..15
    const int c4 = lane & 3;                // 0..3
    ushort* A = gsA[gw];
    ushort* Bs = gsB[gw];

    for (int t6 = 0; t6 < 8; ++t6) {
#pragma unroll 1
      for (int sdx = 0; sdx < 2; ++sdx) {
        const int jp = 2 * wrep + sdx;      // 0..255
        const int b = rep * 16 + (jp & 15);
        const int bn64 = jp >> 4;           // 0..15
        const int m0 = b * 512 + t6 * 64;   // 64 rows, all within batch b
        const int n0 = bn64 * 64;

        float bias[4];
#pragma unroll
        for (int fn = 0; fn < 4; ++fn) {
          int j = n0 + fn * 16 + r16;
          bias[fn] = bih[j] + bhh[j];
        }

        f32x4 acc[4][4] = {};
        for (int kc = 0; kc < 32; ++kc) {
          // stage A (x) and B (Wih) 64x32 f32 -> bf16, padded stride 40
#pragma unroll
          for (int it = 0; it < 4; ++it) {
            int row = it * 16 + r4;
            const float* sa = x + (size_t)(m0 + row) * D_ + kc * 32 + c4 * 8;
            float4 fa0 = *(const float4*)sa;
            float4 fa1 = *(const float4*)(sa + 4);
            union { __hip_bfloat162 h2[4]; uint4 u; } pa;
            pa.h2[0] = __float22bfloat162_rn(make_float2(fa0.x, fa0.y));
            pa.h2[1] = __float22bfloat162_rn(make_float2(fa0.z, fa0.w));
            pa.h2[2] = __float22bfloat162_rn(make_float2(fa1.x, fa1.y));
            pa.h2[3] = __float22bfloat162_rn(make_float2(fa1.z, fa1.w));
            *(uint4*)&A[row * 40 + c4 * 8] = pa.u;
            const float* sb = Wih + (size_t)(n0 + row) * D_ + kc * 32 + c4 * 8;
            float4 fb0 = *(const float4*)sb;
            float4 fb1 = *(const float4*)(sb + 4);
            union { __hip_bfloat162 h2[4]; uint4 u; } pb;
            pb.h2[0] = __float22bfloat162_rn(make_float2(fb0.x, fb0.y));
            pb.h2[1] = __float22bfloat162_rn(make_float2(fb0.z, fb0.w));
            pb.h2[2] = __float22bfloat162_rn(make_float2(fb1.x, fb1.y));
            pb.h2[3] = __float22bfloat162_rn(make_float2(fb1.z, fb1.w));
            *(uint4*)&Bs[row * 40 + c4 * 8] = pb.u;
          }
          // frags + MFMA (same-wave LDS writes/reads are in-order)
          bf16x8 af[4], bfr[4];
#pragma unroll
          for (int fm = 0; fm < 4; ++fm)
            af[fm] = *(const bf16x8*)&A[(fm * 16 + r16) * 40 + kg * 8];
#pragma unroll
          for (int fn = 0; fn < 4; ++fn)
            bfr[fn] = *(const bf16x8*)&Bs[(fn * 16 + r16) * 40 + kg * 8];
#pragma unroll
          for (int fm = 0; fm < 4; ++fm)
#pragma unroll
            for (int fn = 0; fn < 4; ++fn)
              acc[fm][fn] = __builtin_amdgcn_mfma_f32_16x16x32_bf16(
                  af[fm], bfr[fn], acc[fm][fn], 0, 0, 0);
        }

        // epilogue: xp[t][b][j] = acc + bias, sc0 sc1 (cross-XCD consumers)
#pragma unroll
        for (int fm = 0; fm < 4; ++fm) {
#pragma unroll
          for (int r = 0; r < 4; ++r) {
            int mm = fm * 16 + kg * 4 + r;
            int tt = t6 * 64 + mm;
            float* dbase = xp + (size_t)tt * (B_ * H_) + (size_t)b * H_ + n0;
#pragma unroll
            for (int fn = 0; fn < 4; ++fn) {
              float v = acc[fm][fn][r] + bias[fn];
              float* d = dbase + fn * 16 + r16;
              asm volatile("global_store_dword %0, %1, off sc0 sc1"
                           :: "v"(d), "v"(v) : "memory");
            }
          }
        }
        asm volatile("s_waitcnt vmcnt(0)" ::: "memory");
        __builtin_amdgcn_sched_barrier(0);
        if (lane == 0)
          __hip_atomic_store(xpflag + ((size_t)b * 8 + t6) * 16 + bn64, 1u,
                             __ATOMIC_RELAXED, __HIP_MEMORY_SCOPE_AGENT);
      }
      __syncthreads();   // band barrier (8 total)
    }
    // filler barriers to match persist's 512
    for (int q = 0; q < 504; ++q) __syncthreads();
  }
}

// ---------------- launch ----------------
extern "C" void kernel_launch(void* const* d_in, const int* in_sizes, int n_in,
                              void* d_out, int out_size, void* d_ws, size_t ws_size,
                              hipStream_t stream) {
  const float* x    = (const float*)d_in[0];
  const float* W_ih = (const float*)d_in[1];
  const float* W_hh = (const float*)d_in[2];
  const float* b_ih = (const float*)d_in[3];
  const float* b_hh = (const float*)d_in[4];
  float* out = (float*)d_out;

  const size_t xp_bytes  = (size_t)T_ * B_ * H_ * 4;   // 256 MB
  const size_t wsp_bytes = 2 * (size_t)H_ * H_ * 2;    // 4 MB
  const size_t hpk_bytes = 2 * (size_t)B_ * H_ * 4;    // 1 MB
  const size_t cnt_bytes = 256 * 64;                   // 16 KB
  const size_t flg_bytes = 128 * 8 * 16 * 4;           // 64 KB

  if (ws_size < xp_bytes + wsp_bytes + hpk_bytes + cnt_bytes + flg_bytes) return;

  char* p = (char*)d_ws;
  float* xp = (float*)p;                  p += xp_bytes;
  ushort* Whi = (ushort*)p;               p += (size_t)H_ * H_ * 2;
  ushort* Wlo = (ushort*)p;               p += (size_t)H_ * H_ * 2;
  u32* hpk = (u32*)p;                     p += hpk_bytes;
  u32* cnt = (u32*)p;                     p += cnt_bytes;
  u32* xpflag = (u32*)p;

  // 1) split W_hh
  {
    int n = H_ * H_;
    wsplit_kernel<<<(n + 255) / 256, 256, 0, stream>>>(W_hh, Whi, Wlo, n);
  }
  // 2) zero h + counters + xp flags (contiguous; every launch)
  {
    int n4 = (int)((hpk_bytes + cnt_bytes + flg_bytes) / 16);
    hzero_kernel<<<(n4 + 255) / 256, 256, 0, stream>>>((uint4*)hpk, n4);
  }
  // 3) fused gemm + recurrence: 256 WGs x 512 threads
  rnn_fused<<<256, 512, 0, stream>>>(x, W_ih, b_ih, b_hh, Whi, Wlo,
                                     xp, hpk, cnt, xpflag, out);
}

// Round 15
// 2056.021 us; speedup vs baseline: 1.5800x; 1.5800x over previous
//
#include <hip/hip_runtime.h>
#include <hip/hip_bf16.h>
#include <stdint.h>

#define B_ 128
#define T_ 512
#define D_ 1024
#define H_ 1024

typedef __attribute__((ext_vector_type(8))) short bf16x8;
typedef __attribute__((ext_vector_type(4))) float f32x4;
typedef unsigned int u32;
typedef __attribute__((ext_vector_type(4))) u32 u32x4;

__device__ __forceinline__ ushort f2bf(float f) {
  union { float f; uint32_t u; } v; v.f = f;
  uint32_t u = v.u + 0x7FFFu + ((v.u >> 16) & 1u);
  return (ushort)(u >> 16);
}
__device__ __forceinline__ float bf2f(ushort s) {
  union { uint32_t u; float f; } v; v.u = ((uint32_t)s) << 16;
  return v.f;
}

__device__ __forceinline__ void store_xp(float* p, float v) { *p = v; }
__device__ __forceinline__ void store_xp(ushort* p, float v) { *p = f2bf(v); }
__device__ __forceinline__ float load_xp(const float* p) { return *p; }
__device__ __forceinline__ float load_xp(const ushort* p) { return bf2f(*p); }

// ---------------- init: W_hh -> (hi, lo) split + zero h/cnt region ----------------
__global__ void init_kernel(const float* __restrict__ W,
                            ushort* __restrict__ hi, ushort* __restrict__ lo,
                            int nw, uint4* __restrict__ z, int n4) {
  int i = blockIdx.x * blockDim.x + threadIdx.x;
  if (i < nw) {
    float w = W[i];
    ushort h = f2bf(w);
    hi[i] = h;
    lo[i] = f2bf(w - bf2f(h));
  }
  if (i < n4) z[i] = make_uint4(0, 0, 0, 0);
}

// ---------------- xp = x @ W_ih^T + b_ih + b_hh, stored [T,B,H] ----------------
// Grid (8, 512): bn fastest -> the 8 N-tiles of one M-band co-resident, x
// streamed from HBM ~once (round-11 proven).
template <typename XPT>
__global__ __launch_bounds__(256) void xp_gemm(
    const float* __restrict__ x, const float* __restrict__ Wih,
    const float* __restrict__ bih, const float* __restrict__ bhh,
    XPT* __restrict__ xp) {
  __shared__ __align__(16) ushort As[128][40];
  __shared__ __align__(16) ushort Bs[128][40];
  const int tid = threadIdx.x;
  const int lane = tid & 63;
  const int w = tid >> 6;
  const int wm = w >> 1, wn = w & 1;
  const int bn = blockIdx.x;  // 8 N-tiles (fastest -> L2 reuse of x)
  const int bm = blockIdx.y;  // 512 M-tiles

  f32x4 acc[4][4] = {};

  for (int kt = 0; kt < D_ / 32; ++kt) {
    __syncthreads();
#pragma unroll
    for (int i = 0; i < 4; ++i) {
      int c = tid + i * 256;      // 0..1023
      int isB = c >> 9;           // 0: A chunk, 1: B chunk
      int cc = c & 511;
      int row = cc >> 2;          // 0..127
      int col8 = (cc & 3) << 3;   // 0,8,16,24
      const float* src = isB
          ? (Wih + (size_t)(bn * 128 + row) * D_ + kt * 32 + col8)
          : (x + (size_t)(bm * 128 + row) * D_ + kt * 32 + col8);
      float4 f0 = *(const float4*)(src);
      float4 f1 = *(const float4*)(src + 4);
      union { __hip_bfloat162 h2[4]; uint4 u; } pk;
      pk.h2[0] = __float22bfloat162_rn(make_float2(f0.x, f0.y));
      pk.h2[1] = __float22bfloat162_rn(make_float2(f0.z, f0.w));
      pk.h2[2] = __float22bfloat162_rn(make_float2(f1.x, f1.y));
      pk.h2[3] = __float22bfloat162_rn(make_float2(f1.z, f1.w));
      ushort* dst = isB ? &Bs[row][col8] : &As[row][col8];
      *(uint4*)dst = pk.u;
    }
    __syncthreads();

    bf16x8 af[4], bfr[4];
#pragma unroll
    for (int fm = 0; fm < 4; ++fm)
      af[fm] = *(const bf16x8*)&As[wm * 64 + fm * 16 + (lane & 15)][(lane >> 4) * 8];
#pragma unroll
    for (int fn = 0; fn < 4; ++fn)
      bfr[fn] = *(const bf16x8*)&Bs[wn * 64 + fn * 16 + (lane & 15)][(lane >> 4) * 8];
#pragma unroll
    for (int fm = 0; fm < 4; ++fm)
#pragma unroll
      for (int fn = 0; fn < 4; ++fn)
        acc[fm][fn] = __builtin_amdgcn_mfma_f32_16x16x32_bf16(
            af[fm], bfr[fn], acc[fm][fn], 0, 0, 0);
  }

  float bias[4];
#pragma unroll
  for (int fn = 0; fn < 4; ++fn) {
    int j = bn * 128 + wn * 64 + fn * 16 + (lane & 15);
    bias[fn] = bih[j] + bhh[j];
  }
#pragma unroll
  for (int fm = 0; fm < 4; ++fm) {
#pragma unroll
    for (int r = 0; r < 4; ++r) {
      int m = bm * 128 + wm * 64 + fm * 16 + ((lane >> 4) * 4) + r;
      int t = m & (T_ - 1);
      int b = m >> 9;  // m / T_
      size_t base = (size_t)t * (B_ * H_) + (size_t)b * H_;
#pragma unroll
      for (int fn = 0; fn < 4; ++fn) {
        int j = bn * 128 + wn * 64 + fn * 16 + (lane & 15);
        store_xp(xp + base + j, acc[fm][fn][r] + bias[fn]);
      }
    }
  }
}

// ---------------- persistent recurrence (round-11 best: 1690 us) ----------------
// 256 WGs: replica = bid&7 (16 batches), wgc = bid>>3 (32 cols). Wave = K-quarter.
// Per-wave producer poll (8 WGs x 4 slots via 32 lanes); posts are plain relaxed
// agent STORES (value t+1 into slot kq of own WG line) - no RMW serialization.
// WAR invariant: union of the 4 waves' poll sets = all 128 wave-posts of the
// replica checked >= t before __syncthreads -> h-buffer write safe.
template <typename XPT>
__global__ __launch_bounds__(256, 1) void rnn_persist(
    const ushort* __restrict__ Whi, const ushort* __restrict__ Wlo,
    const XPT* __restrict__ xp,
    u32* __restrict__ hpk,   // [2][B_][H_] packed bf16 hi|lo
    u32* __restrict__ cnt,   // [256][16]: line (rep*32+wgc), slots 0..3 = waves
    float* __restrict__ out) {
  __shared__ __align__(16) u32 stage[4 * 16 * 256];      // 64 KB
  __shared__ __align__(16) f32x4 red[2][4][2][64];       // 16 KB

  const int bid = blockIdx.x;
  const int rep = bid & 7;    // batches [rep*16, rep*16+16)
  const int wgc = bid >> 3;   // cols [wgc*32, wgc*32+32)
  const int tid = threadIdx.x;
  const int lane = tid & 63;
  const int kq = tid >> 6;    // wave = K-quarter
  const int r16 = lane & 15;
  const int kg = lane >> 4;   // 0..3
  const int nf_e = kq & 1;    // epilogue: nf slice
  const int rh_e = kq >> 1;   // epilogue: row pair
  const int l5 = lane & 31;

  // ---- preload W fragments into registers (128 VGPR) ----
  bf16x8 wbh[8][2], wbl[8][2];
#pragma unroll
  for (int ks = 0; ks < 8; ++ks) {
#pragma unroll
    for (int nf = 0; nf < 2; ++nf) {
      int col = wgc * 32 + nf * 16 + r16;
      int k = kq * 256 + ks * 32 + kg * 8;
      wbh[ks][nf] = *(const bf16x8*)(Whi + (size_t)col * H_ + k);
      wbl[ks][nf] = *(const bf16x8*)(Wlo + (size_t)col * H_ + k);
    }
  }

  const int erow0 = rep * 16 + kg * 4 + rh_e * 2;
  const int ecol = wgc * 32 + nf_e * 16 + r16;
  u32* mypost = cnt + (size_t)(rep * 32 + wgc) * 16 + kq;
  const u32* mypoll = cnt + (size_t)(rep * 32 + kq * 8 + (l5 >> 2)) * 16 + (l5 & 3);
  const int sbase = kq * (16 * 256);

  for (int t = 0; t < T_; ++t) {
    const u32* Hq = hpk + (size_t)(t & 1) * (B_ * H_);
    u32* Hn = hpk + (size_t)((t + 1) & 1) * (B_ * H_);

    // ---- per-wave poll: my quarter's 8 producer WGs x 4 wave-slots >= t ----
    if (t) {
      const u32 target = (u32)t;
      for (;;) {
        u32 v = __hip_atomic_load(mypoll, __ATOMIC_RELAXED, __HIP_MEMORY_SCOPE_AGENT);
        if (__all((int)(v >= target))) break;
        __builtin_amdgcn_s_sleep(1);
      }
    }

    // xp prefetch (issued first -> oldest in vmcnt order)
    float xpv[2];
#pragma unroll
    for (int e = 0; e < 2; ++e)
      xpv[e] = load_xp(xp + (size_t)t * (B_ * H_) + (size_t)(erow0 + e) * H_ + ecol);

    // ---- coalesced gather: wave kq pulls its 16-row x 256-col u32 quarter ----
    u32x4 g[16];
    {
      const u32* gb = Hq + (size_t)rep * 16 * H_ + kq * 256 + lane * 4;
#pragma unroll
      for (int i = 0; i < 16; ++i) {
        const u32* a = gb + (size_t)i * H_;
        asm volatile("global_load_dwordx4 %0, %1, off sc0 sc1"
                     : "=&v"(g[i]) : "v"(a) : "memory");
      }
    }
    // chunked drain: xp(2) + 16 gathers outstanding; vmcnt(8) = oldest 10 done
    asm volatile("s_waitcnt vmcnt(8)" ::: "memory");
    __builtin_amdgcn_sched_barrier(0);
#pragma unroll
    for (int i = 0; i < 8; ++i) {
      int idx = sbase + i * 256 + ((lane * 4) ^ ((i & 7) << 2));
      *(u32x4*)&stage[idx] = g[i];
    }
    asm volatile("s_waitcnt vmcnt(0)" ::: "memory");
    __builtin_amdgcn_sched_barrier(0);
#pragma unroll
    for (int i = 8; i < 16; ++i) {
      int idx = sbase + i * 256 + ((lane * 4) ^ ((i & 7) << 2));
      *(u32x4*)&stage[idx] = g[i];
    }

    // ---- A-frags from LDS + MFMA (DS in-order per wave; no barrier) ----
    f32x4 acc[2] = {};
    const int rbase = sbase + r16 * 256;
    const int s = (r16 & 7) << 2;
#pragma unroll
    for (int ks = 0; ks < 8; ++ks) {
      int colq = ks * 32 + kg * 8;
      u32x4 d0 = *(const u32x4*)&stage[rbase + ((colq) ^ s)];
      u32x4 d1 = *(const u32x4*)&stage[rbase + ((colq + 4) ^ s)];
      union { u32 u[4]; bf16x8 v; } ah, al;
      ah.u[0] = __builtin_amdgcn_perm(d0[1], d0[0], 0x05040100u);
      ah.u[1] = __builtin_amdgcn_perm(d0[3], d0[2], 0x05040100u);
      ah.u[2] = __builtin_amdgcn_perm(d1[1], d1[0], 0x05040100u);
      ah.u[3] = __builtin_amdgcn_perm(d1[3], d1[2], 0x05040100u);
      al.u[0] = __builtin_amdgcn_perm(d0[1], d0[0], 0x07060302u);
      al.u[1] = __builtin_amdgcn_perm(d0[3], d0[2], 0x07060302u);
      al.u[2] = __builtin_amdgcn_perm(d1[1], d1[0], 0x07060302u);
      al.u[3] = __builtin_amdgcn_perm(d1[3], d1[2], 0x07060302u);
#pragma unroll
      for (int nf = 0; nf < 2; ++nf) {
        acc[nf] = __builtin_amdgcn_mfma_f32_16x16x32_bf16(ah.v, wbh[ks][nf], acc[nf], 0, 0, 0);
        acc[nf] = __builtin_amdgcn_mfma_f32_16x16x32_bf16(al.v, wbh[ks][nf], acc[nf], 0, 0, 0);
        acc[nf] = __builtin_amdgcn_mfma_f32_16x16x32_bf16(ah.v, wbl[ks][nf], acc[nf], 0, 0, 0);
      }
    }

    // ---- all-to-all K reduce (parity double-buffered, one barrier) ----
    const int par = t & 1;
    red[par][kq][0][lane] = acc[0];
    red[par][kq][1][lane] = acc[1];
    __syncthreads();   // joins all 4 waves => all 32 producers done (safety)

    // ---- parallel epilogue: vector red reads + uniform select ----
    {
      f32x4 sum = red[par][0][nf_e][lane];
      sum += red[par][1][nf_e][lane];
      sum += red[par][2][nf_e][lane];
      sum += red[par][3][nf_e][lane];
      float s0 = rh_e ? sum[2] : sum[0];
      float s1 = rh_e ? sum[3] : sum[1];
      float h0 = tanhf(s0 + xpv[0]);
      float h1 = tanhf(s1 + xpv[1]);
      ushort hb0 = f2bf(h0), hb1 = f2bf(h1);
      u32 pk0 = (u32)hb0 | ((u32)f2bf(h0 - bf2f(hb0)) << 16);
      u32 pk1 = (u32)hb1 | ((u32)f2bf(h1 - bf2f(hb1)) << 16);
      __hip_atomic_store(Hn + (size_t)erow0 * H_ + ecol, pk0,
                         __ATOMIC_RELAXED, __HIP_MEMORY_SCOPE_AGENT);
      __hip_atomic_store(Hn + (size_t)(erow0 + 1) * H_ + ecol, pk1,
                         __ATOMIC_RELAXED, __HIP_MEMORY_SCOPE_AGENT);
      if (t == T_ - 1) {
        out[(size_t)erow0 * H_ + ecol] = h0;
        out[(size_t)(erow0 + 1) * H_ + ecol] = h1;
      }
    }

    // ---- completion: drain stores, post own wave slot (plain store) ----
    asm volatile("s_waitcnt vmcnt(0)" ::: "memory");
    __builtin_amdgcn_sched_barrier(0);
    if (lane == 0)
      __hip_atomic_store(mypost, (u32)(t + 1),
                         __ATOMIC_RELAXED, __HIP_MEMORY_SCOPE_AGENT);
  }
}

// ---------------- launch ----------------
extern "C" void kernel_launch(void* const* d_in, const int* in_sizes, int n_in,
                              void* d_out, int out_size, void* d_ws, size_t ws_size,
                              hipStream_t stream) {
  const float* x    = (const float*)d_in[0];
  const float* W_ih = (const float*)d_in[1];
  const float* W_hh = (const float*)d_in[2];
  const float* b_ih = (const float*)d_in[3];
  const float* b_hh = (const float*)d_in[4];
  float* out = (float*)d_out;

  const size_t xp_f32_bytes = (size_t)T_ * B_ * H_ * 4;   // 256 MB
  const size_t xp_bf_bytes  = xp_f32_bytes / 2;           // 128 MB
  const size_t wsp_bytes    = 2 * (size_t)H_ * H_ * 2;    // 4 MB (hi+lo)
  const size_t hpk_bytes    = 2 * (size_t)B_ * H_ * 4;    // 1 MB packed dbuf
  const size_t cnt_bytes    = 256 * 64;                   // 16 KB

  bool fp32xp = ws_size >= xp_f32_bytes + wsp_bytes + hpk_bytes + cnt_bytes;
  bool bf16xp = !fp32xp && ws_size >= xp_bf_bytes + wsp_bytes + hpk_bytes + cnt_bytes;
  if (!fp32xp && !bf16xp) return;

  char* p = (char*)d_ws;
  size_t xp_bytes = fp32xp ? xp_f32_bytes : xp_bf_bytes;
  char* xp_raw = p;                       p += xp_bytes;
  ushort* Whi = (ushort*)p;               p += (size_t)H_ * H_ * 2;
  ushort* Wlo = (ushort*)p;               p += (size_t)H_ * H_ * 2;
  u32* hpk = (u32*)p;                     p += hpk_bytes;
  u32* cnt = (u32*)p;

  // 1) fused init: W_hh split + zero h/cnt (one launch)
  {
    int nw = H_ * H_;
    int n4 = (int)((hpk_bytes + cnt_bytes) / 16);
    int n = nw > n4 ? nw : n4;
    init_kernel<<<(n + 255) / 256, 256, 0, stream>>>(W_hh, Whi, Wlo, nw,
                                                     (uint4*)hpk, n4);
  }
  // 2) xp GEMM — transposed grid: bn fastest so x is read from HBM ~once
  dim3 gxp(8, 512);
  if (fp32xp)
    xp_gemm<float><<<gxp, 256, 0, stream>>>(x, W_ih, b_ih, b_hh, (float*)xp_raw);
  else
    xp_gemm<ushort><<<gxp, 256, 0, stream>>>(x, W_ih, b_ih, b_hh, (ushort*)xp_raw);

  // 3) persistent recurrence (256 WGs, 1 WG/CU)
  if (fp32xp)
    rnn_persist<float><<<256, 256, 0, stream>>>(Whi, Wlo, (const float*)xp_raw,
                                                hpk, cnt, out);
  else
    rnn_persist<ushort><<<256, 256, 0, stream>>>(Whi, Wlo, (const ushort*)xp_raw,
                                                 hpk, cnt, out);
}